// Round 9
// baseline (464.046 us; speedup 1.0000x reference)
//
#include <hip/hip_runtime.h>

// Problem constants (from reference)
#define B_TREES 32
#define DEPTH   12
#define M_NODES 4095                  // 2^12 - 1
#define N_NODES (B_TREES * M_NODES)   // 131040
#define HDIM    256
#define VOCAB   32000
#define NCLS    20
#define LEAFROWS 65536                // 32 * 2048 leaves
#define LDSH_S 20                     // padded stride of h transpose tiles

typedef _Float16 f16;
typedef _Float16 f16x8 __attribute__((ext_vector_type(8)));
typedef _Float16 f16x4 __attribute__((ext_vector_type(4)));
typedef _Float16 f16x2 __attribute__((ext_vector_type(2)));
typedef float    f32x4 __attribute__((ext_vector_type(4)));

__device__ __forceinline__ float sigf(float x)      { return 1.0f / (1.0f + __expf(-x)); }
__device__ __forceinline__ float tanh_fast(float x) { return 1.0f - 2.0f / (1.0f + __expf(2.0f * x)); }

// ---------------------------------------------------------------------------
// Init: convert Emb + weights to fp16. W_out padded to 32 rows (zeros).
// ---------------------------------------------------------------------------
__global__ __launch_bounds__(256) void cvt_kernel(
    const float4* __restrict__ Emb,  const float4* __restrict__ Wiou,
    const float4* __restrict__ Uiou, const float4* __restrict__ Uf,
    const float4* __restrict__ Wout,
    f16x4* __restrict__ Emb16,  f16x4* __restrict__ Wiou16,
    f16x4* __restrict__ Uiou16, f16x4* __restrict__ Uf16,
    f16x4* __restrict__ Wout16)
{
    int i = blockIdx.x * 256 + threadIdx.x;   // in units of 4 floats
    if (i < VOCAB * HDIM / 4) {
        float4 v = Emb[i];
        f16x4 r; r[0] = (f16)v.x; r[1] = (f16)v.y; r[2] = (f16)v.z; r[3] = (f16)v.w;
        Emb16[i] = r;
    }
    if (i < 768 * HDIM / 4) {
        float4 v = Wiou[i];
        f16x4 r; r[0] = (f16)v.x; r[1] = (f16)v.y; r[2] = (f16)v.z; r[3] = (f16)v.w;
        Wiou16[i] = r;
        float4 u = Uiou[i];
        f16x4 s; s[0] = (f16)u.x; s[1] = (f16)u.y; s[2] = (f16)u.z; s[3] = (f16)u.w;
        Uiou16[i] = s;
    }
    if (i < HDIM * HDIM / 4) {
        float4 v = Uf[i];
        f16x4 r; r[0] = (f16)v.x; r[1] = (f16)v.y; r[2] = (f16)v.z; r[3] = (f16)v.w;
        Uf16[i] = r;
    }
    if (i < 32 * HDIM / 4) {                  // 32 padded rows of W_out
        int row = i >> 6;
        f16x4 r = {};
        if (row < NCLS) {
            float4 v = Wout[i];
            r[0] = (f16)v.x; r[1] = (f16)v.y; r[2] = (f16)v.z; r[3] = (f16)v.w;
        }
        Wout16[i] = r;
    }
}

// ---------------------------------------------------------------------------
// Leaf kernel: block owns 16 output cols; Wiou 16-col tile (3 gates, 24 KB)
// staged in LDS in MFMA-fragment order. Each wave loops 8 row-tiles of 16
// leaves with 1-deep A-prefetch. Grid (16, 128): col-block is grid.x so the
// 16 blocks re-gathering the same Emb rows are dispatch-adjacent (L2 reuse).
// ---------------------------------------------------------------------------
#define LEAF_TPW 8
__global__ __launch_bounds__(256) void leaf_kernel(
    const int* __restrict__ x, const f16* __restrict__ Emb16,
    const f16* __restrict__ Wiou16, const float* __restrict__ b_iou,
    f16* __restrict__ h16, f16* __restrict__ cT)
{
    __shared__ f16 wlds[1536 * 8];             // 24 KB: [mat][ks][quad][col] frags
    __shared__ f16 ldsh[4][16 * LDSH_S];

    const int tid  = threadIdx.x;
    const int lane = tid & 63;
    const int w    = tid >> 6;
    const int quad = lane >> 4;
    const int l15  = lane & 15;
    const int qk   = quad * 8;
    const int cb0  = blockIdx.x * 16;          // block's 16 cols

    // Stage weights (frag f = mat*512 + ks*64 + quad*16 + col)
    #pragma unroll
    for (int i = 0; i < 6; ++i) {
        int f = i * 256 + tid;
        int mat = f >> 9, r = f & 511, ks = r >> 6, q = (r >> 4) & 3, c = r & 15;
        *(f16x8*)(wlds + f * 8) = *(const f16x8*)(Wiou16 +
            (mat * 256 + cb0 + c) * HDIM + ks * 32 + q * 8);
    }
    __syncthreads();

    const float bi = b_iou[cb0 + l15];
    const float bo = b_iou[256 + cb0 + l15];
    const float bu = b_iou[512 + cb0 + l15];

    const int row0 = (blockIdx.y * 4 + w) * (LEAF_TPW * 16);  // wave's rows

    // Prefetch tile 0 (16 leaf rows are node-contiguous: 16 | 2048)
    int nodeRow = (row0 >> 11) * M_NODES + 2047 + (row0 & 2047);
    int embBase = x[nodeRow + l15] * HDIM;
    f16x8 a[8];
    #pragma unroll
    for (int ks = 0; ks < 8; ++ks)
        a[ks] = *(const f16x8*)(Emb16 + embBase + ks * 32 + qk);

    for (int rt = 0; rt < LEAF_TPW; ++rt) {
        const int rw = row0 + rt * 16;
        const int curNode = nodeRow;
        f16x8 ac[8];
        #pragma unroll
        for (int ks = 0; ks < 8; ++ks) ac[ks] = a[ks];

        if (rt + 1 < LEAF_TPW) {               // prefetch next tile
            const int rwn = rw + 16;
            nodeRow = (rwn >> 11) * M_NODES + 2047 + (rwn & 2047);
            embBase = x[nodeRow + l15] * HDIM;
            #pragma unroll
            for (int ks = 0; ks < 8; ++ks)
                a[ks] = *(const f16x8*)(Emb16 + embBase + ks * 32 + qk);
        }

        f32x4 acc[3] = {};
        #pragma unroll
        for (int ks = 0; ks < 8; ++ks) {
            #pragma unroll
            for (int mat = 0; mat < 3; ++mat) {
                f16x8 wf = *(const f16x8*)(wlds +
                    ((mat * 8 + ks) * 64 + quad * 16 + l15) * 8);
                acc[mat] = __builtin_amdgcn_mfma_f32_16x16x32_f16(
                    ac[ks], wf, acc[mat], 0, 0, 0);
            }
        }

        // Epilogue (leaves: h_sum = fc_sum = 0)
        f16x4 cv;
        #pragma unroll
        for (int r = 0; r < 4; ++r) {
            float i_ = acc[0][r] + bi;
            float o_ = acc[1][r] + bo;
            float u_ = acc[2][r] + bu;
            float c  = sigf(i_) * tanh_fast(u_);
            float h  = sigf(o_) * tanh_fast(c);
            cv[r] = (f16)c;
            ldsh[w][(quad * 4 + r) * LDSH_S + l15] = (f16)h;
        }
        *(f16x4*)(cT + (cb0 + l15) * LEAFROWS + rw + quad * 4) = cv;

        // Wave-local drain of 16x16 h tile (8B stores)
        {
            int row_l = lane >> 2, cpos = (lane & 3) * 4;
            f16x4 v = *(const f16x4*)(&ldsh[w][row_l * LDSH_S + cpos]);
            *(f16x4*)(h16 + (curNode + row_l) * HDIM + cb0 + cpos) = v;
        }
    }
}

// ---------------------------------------------------------------------------
// Fused level kernel (round-7 datapath): block owns 16 cols. Work unit =
// 16 parents (32 children). Single K-loop reads the 32 child-h rows once;
// each weight fragment feeds 2 MFMAs (a0, a1). Parent iou = in-lane
// pair-sum of adjacent C/D regs; fc = f0*c0+f1*c1 in-lane.
// STAGE: weights in LDS (big levels) vs direct L2-hot global (small levels).
// Grid (16, gy): col-major dispatch for child-h L2 reuse.
// ---------------------------------------------------------------------------
template <bool STAGE>
__global__ __launch_bounds__(256) void fused_level_kernel(
    const f16* __restrict__ Uiou16, const f16* __restrict__ Uf16,
    const float* __restrict__ b_iou, const float* __restrict__ b_f,
    f16* __restrict__ h16, const f16* __restrict__ cT_child,
    f16* __restrict__ cT_parent, int l, int rows_p, int tpw)
{
    __shared__ f16 wlds[STAGE ? 2048 * 8 : 8]; // 32 KB: mat0=Uf, mat1..3=Uiou
    __shared__ f16 ldsh[4][16 * LDSH_S];

    const int tid  = threadIdx.x;
    const int lane = tid & 63;
    const int w    = tid >> 6;
    const int quad = lane >> 4;
    const int l15  = lane & 15;
    const int qk   = quad * 8;
    const int cb0  = blockIdx.x * 16;

    if (STAGE) {
        #pragma unroll
        for (int i = 0; i < 8; ++i) {
            int f = i * 256 + tid;
            int mat = f >> 9, r = f & 511, ks = r >> 6, q = (r >> 4) & 3, c = r & 15;
            const f16* src = (mat == 0)
                ? (Uf16 + (cb0 + c) * HDIM + ks * 32 + q * 8)
                : (Uiou16 + ((mat - 1) * 256 + cb0 + c) * HDIM + ks * 32 + q * 8);
            *(f16x8*)(wlds + f * 8) = *(const f16x8*)src;
        }
        __syncthreads();
    }

    const float bi  = b_iou[cb0 + l15];
    const float bo  = b_iou[256 + cb0 + l15];
    const float bu  = b_iou[512 + cb0 + l15];
    const float bfv = b_f[cb0 + l15];
    const int lc = l + 1;
    const int maskc = (1 << lc) - 1;
    const int maskp = (1 << l) - 1;
    const int rows_c = rows_p * 2;
    const int tiles  = rows_p >> 4;            // 16 parents per tile

    const int t0 = (blockIdx.y * 4 + w) * tpw;
    const int nt = (t0 >= tiles) ? 0 : ((tiles - t0 < tpw) ? tiles - t0 : tpw);

    for (int i = 0; i < nt; ++i) {
        const int pw = (t0 + i) * 16;          // tile's first parent
        const int cw = 2 * pw;

        int childBase0, childBase1;
        {
            int cl0 = cw + l15;
            childBase0 = ((cl0 >> lc) * M_NODES + maskc + (cl0 & maskc)) * HDIM;
            int cl1 = cw + 16 + l15;
            childBase1 = ((cl1 >> lc) * M_NODES + maskc + (cl1 & maskc)) * HDIM;
        }

        f32x4 accf0 = {}, accf1 = {};
        f32x4 au0[3] = {}, au1[3] = {};
        #pragma unroll
        for (int ks = 0; ks < 8; ++ks) {
            const int k0 = ks * 32 + qk;
            f16x8 a0 = *(const f16x8*)(h16 + childBase0 + k0);
            f16x8 a1 = *(const f16x8*)(h16 + childBase1 + k0);
            f16x8 wfF = STAGE
                ? *(const f16x8*)(wlds + (ks * 64 + quad * 16 + l15) * 8)
                : *(const f16x8*)(Uf16 + (cb0 + l15) * HDIM + k0);
            accf0 = __builtin_amdgcn_mfma_f32_16x16x32_f16(a0, wfF, accf0, 0, 0, 0);
            accf1 = __builtin_amdgcn_mfma_f32_16x16x32_f16(a1, wfF, accf1, 0, 0, 0);
            #pragma unroll
            for (int m = 0; m < 3; ++m) {
                f16x8 wm = STAGE
                    ? *(const f16x8*)(wlds + (((m + 1) * 8 + ks) * 64 + quad * 16 + l15) * 8)
                    : *(const f16x8*)(Uiou16 + (m * 256 + cb0 + l15) * HDIM + k0);
                au0[m] = __builtin_amdgcn_mfma_f32_16x16x32_f16(a0, wm, au0[m], 0, 0, 0);
                au1[m] = __builtin_amdgcn_mfma_f32_16x16x32_f16(a1, wm, au1[m], 0, 0, 0);
            }
        }

        // Epilogue: two child sets -> parents pw..pw+7 and pw+8..pw+15
        #pragma unroll
        for (int s = 0; s < 2; ++s) {
            const f32x4& af = s ? accf1 : accf0;
            const f32x4* au = s ? au1 : au0;
            const int csr = cw + s * 16;          // child rows of this set
            f16x4 cc = *(const f16x4*)(cT_child +
                (cb0 + l15) * rows_c + csr + quad * 4);
            f16x2 cpack;
            #pragma unroll
            for (int pr = 0; pr < 2; ++pr) {
                float f0 = sigf(af[2 * pr]     + bfv);
                float f1 = sigf(af[2 * pr + 1] + bfv);
                float fc = f0 * (float)cc[2 * pr] + f1 * (float)cc[2 * pr + 1];
                float i_ = au[0][2 * pr] + au[0][2 * pr + 1] + bi;
                float o_ = au[1][2 * pr] + au[1][2 * pr + 1] + bo;
                float u_ = au[2][2 * pr] + au[2][2 * pr + 1] + bu;
                float c  = sigf(i_) * tanh_fast(u_) + fc;
                float h  = sigf(o_) * tanh_fast(c);
                cpack[pr] = (f16)c;
                ldsh[w][(s * 8 + quad * 2 + pr) * LDSH_S + l15] = (f16)h;
            }
            *(f16x2*)(cT_parent + (cb0 + l15) * rows_p + pw + s * 8 + quad * 2) = cpack;
        }

        // Wave-local drain of 16-parent x 16-col h tile (8B stores)
        {
            int prow = lane >> 2, cpos = (lane & 3) * 4;
            int p = pw + prow;
            int b = p >> l, tt = p & maskp;
            int node = b * M_NODES + (1 << l) - 1 + tt;
            f16x4 v = *(const f16x4*)(&ldsh[w][prow * LDSH_S + cpos]);
            *(f16x4*)(h16 + node * HDIM + cb0 + cpos) = v;
        }
    }
}

// ---------------------------------------------------------------------------
// Output: out = h_all @ W_out^T + b_out (N padded 20->32). Persistent
// weights (64 VGPRs); wave owns 4 consecutive tiles with 1-deep prefetch.
// ---------------------------------------------------------------------------
__global__ __launch_bounds__(256) void out_kernel(
    const f16* __restrict__ h16, const f16* __restrict__ Wout16,
    const float* __restrict__ bout, float* __restrict__ out)
{
    const int lane = threadIdx.x & 63;
    const int w    = threadIdx.x >> 6;
    const int quad = lane >> 4;
    const int l15  = lane & 15;
    const int qk   = quad * 8;

    f16x8 wfk[2][8];
    #pragma unroll
    for (int cf = 0; cf < 2; ++cf)
        #pragma unroll
        for (int ks = 0; ks < 8; ++ks)
            wfk[cf][ks] = *(const f16x8*)(Wout16 +
                (cf * 16 + l15) * HDIM + ks * 32 + qk);
    float bo[2];
    #pragma unroll
    for (int cf = 0; cf < 2; ++cf) {
        int col = cf * 16 + l15;
        bo[cf] = bout[col < NCLS ? col : 0];
    }

    const int ntotal = N_NODES / 16;               // 8190
    const int t0     = blockIdx.x * 16 + w * 4;    // wave's first tile
    const int tn     = (t0 >= ntotal) ? 0 : ((ntotal - t0 < 4) ? ntotal - t0 : 4);
    if (tn <= 0) return;

    f16x8 a[8];
    #pragma unroll
    for (int ks = 0; ks < 8; ++ks)
        a[ks] = *(const f16x8*)(h16 + (t0 * 16 + l15) * HDIM + ks * 32 + qk);

    for (int i = 0; i < tn; ++i) {
        const int rw = (t0 + i) * 16;
        f16x8 ac[8];
        #pragma unroll
        for (int ks = 0; ks < 8; ++ks) ac[ks] = a[ks];

        {
            const int tnx = (i + 1 < tn) ? t0 + i + 1 : t0 + i;
            #pragma unroll
            for (int ks = 0; ks < 8; ++ks)
                a[ks] = *(const f16x8*)(h16 + (tnx * 16 + l15) * HDIM + ks * 32 + qk);
        }

        f32x4 acc[2] = {};
        #pragma unroll
        for (int ks = 0; ks < 8; ++ks)
            #pragma unroll
            for (int cf = 0; cf < 2; ++cf)
                acc[cf] = __builtin_amdgcn_mfma_f32_16x16x32_f16(
                    ac[ks], wfk[cf][ks], acc[cf], 0, 0, 0);

        #pragma unroll
        for (int cf = 0; cf < 2; ++cf) {
            const int col = cf * 16 + l15;
            if (col < NCLS) {
                #pragma unroll
                for (int r = 0; r < 4; ++r)
                    out[(rw + quad * 4 + r) * NCLS + col] = acc[cf][r] + bo[cf];
            }
        }
    }
}

// ---------------------------------------------------------------------------
extern "C" void kernel_launch(void* const* d_in, const int* in_sizes, int n_in,
                              void* d_out, int out_size, void* d_ws, size_t ws_size,
                              hipStream_t stream)
{
    const int*   x     = (const int*)d_in[0];
    // d_in[1] = x_mask: leaf structure is static — folded into indexing.
    const float* Emb   = (const float*)d_in[2];
    const float* W_iou = (const float*)d_in[3];
    const float* b_iou = (const float*)d_in[4];
    const float* U_iou = (const float*)d_in[5];
    const float* U_f   = (const float*)d_in[6];
    const float* b_f   = (const float*)d_in[7];
    const float* W_out = (const float*)d_in[8];
    const float* b_out = (const float*)d_in[9];
    float* out = (float*)d_out;

    char* ws = (char*)d_ws;
    size_t off = 0;
    auto take = [&](size_t bytes) -> char* {
        char* p = ws + off; off += (bytes + 255) & ~(size_t)255; return p;
    };
    f16* h16    = (f16*)take((size_t)N_NODES * HDIM * 2);
    f16* cA     = (f16*)take((size_t)HDIM * LEAFROWS * 2);        // [256][65536]
    f16* cB     = (f16*)take((size_t)HDIM * (LEAFROWS / 2) * 2);  // [256][32768]
    f16* Emb16  = (f16*)take((size_t)VOCAB * HDIM * 2);
    f16* Wiou16 = (f16*)take((size_t)768 * HDIM * 2);
    f16* Uiou16 = (f16*)take((size_t)768 * HDIM * 2);
    f16* Uf16   = (f16*)take((size_t)HDIM * HDIM * 2);
    f16* Wout16 = (f16*)take((size_t)32 * HDIM * 2);

    cvt_kernel<<<VOCAB * HDIM / 4 / 256, 256, 0, stream>>>(
        (const float4*)Emb, (const float4*)W_iou, (const float4*)U_iou,
        (const float4*)U_f, (const float4*)W_out,
        (f16x4*)Emb16, (f16x4*)Wiou16, (f16x4*)Uiou16, (f16x4*)Uf16,
        (f16x4*)Wout16);

    // Leaves: grid (16 col-blocks, 128 row-chunks)
    leaf_kernel<<<dim3(16, LEAFROWS / (4 * 16 * LEAF_TPW)), 256, 0, stream>>>(
        x, Emb16, Wiou16, b_iou, h16, cA);

    // Levels 10..0, fused fgate+iou, ping-pong transposed c buffers
    f16* cin  = cA;
    f16* cout_ = cB;
    for (int l = 10; l >= 0; --l) {
        int rows_p = B_TREES << l;
        int tiles  = rows_p >> 4;
        int tpw    = tiles / 256; if (tpw < 1) tpw = 1;
        int gy     = (tiles + 4 * tpw - 1) / (4 * tpw);
        if (tiles >= 512)
            fused_level_kernel<true><<<dim3(16, gy), 256, 0, stream>>>(
                Uiou16, Uf16, b_iou, b_f, h16, cin, cout_, l, rows_p, tpw);
        else
            fused_level_kernel<false><<<dim3(16, gy), 256, 0, stream>>>(
                Uiou16, Uf16, b_iou, b_f, h16, cin, cout_, l, rows_p, tpw);
        f16* t = cin; cin = cout_; cout_ = t;
    }

    out_kernel<<<dim3((N_NODES / 16 + 15) / 16), 256, 0, stream>>>(
        h16, Wout16, b_out, out);
}

// Round 10
// 420.823 us; speedup vs baseline: 1.1027x; 1.1027x over previous
//
#include <hip/hip_runtime.h>

// Problem constants (from reference)
#define B_TREES 32
#define DEPTH   12
#define M_NODES 4095                  // 2^12 - 1
#define N_NODES (B_TREES * M_NODES)   // 131040
#define HDIM    256
#define VOCAB   32000
#define NCLS    20
#define LEAFROWS 65536                // 32 * 2048 leaves
#define LDSH_S 20                     // padded stride of h transpose tiles

typedef _Float16 f16;
typedef _Float16 f16x8 __attribute__((ext_vector_type(8)));
typedef _Float16 f16x4 __attribute__((ext_vector_type(4)));
typedef _Float16 f16x2 __attribute__((ext_vector_type(2)));
typedef float    f32x4 __attribute__((ext_vector_type(4)));

__device__ __forceinline__ float sigf(float x)      { return 1.0f / (1.0f + __expf(-x)); }
__device__ __forceinline__ float tanh_fast(float x) { return 1.0f - 2.0f / (1.0f + __expf(2.0f * x)); }

// ---------------------------------------------------------------------------
// Init: convert Emb + weights to fp16. W_out padded to 32 rows (zeros).
// ---------------------------------------------------------------------------
__global__ __launch_bounds__(256) void cvt_kernel(
    const float4* __restrict__ Emb,  const float4* __restrict__ Wiou,
    const float4* __restrict__ Uiou, const float4* __restrict__ Uf,
    const float4* __restrict__ Wout,
    f16x4* __restrict__ Emb16,  f16x4* __restrict__ Wiou16,
    f16x4* __restrict__ Uiou16, f16x4* __restrict__ Uf16,
    f16x4* __restrict__ Wout16)
{
    int i = blockIdx.x * 256 + threadIdx.x;   // in units of 4 floats
    if (i < VOCAB * HDIM / 4) {
        float4 v = Emb[i];
        f16x4 r; r[0] = (f16)v.x; r[1] = (f16)v.y; r[2] = (f16)v.z; r[3] = (f16)v.w;
        Emb16[i] = r;
    }
    if (i < 768 * HDIM / 4) {
        float4 v = Wiou[i];
        f16x4 r; r[0] = (f16)v.x; r[1] = (f16)v.y; r[2] = (f16)v.z; r[3] = (f16)v.w;
        Wiou16[i] = r;
        float4 u = Uiou[i];
        f16x4 s; s[0] = (f16)u.x; s[1] = (f16)u.y; s[2] = (f16)u.z; s[3] = (f16)u.w;
        Uiou16[i] = s;
    }
    if (i < HDIM * HDIM / 4) {
        float4 v = Uf[i];
        f16x4 r; r[0] = (f16)v.x; r[1] = (f16)v.y; r[2] = (f16)v.z; r[3] = (f16)v.w;
        Uf16[i] = r;
    }
    if (i < 32 * HDIM / 4) {                  // 32 padded rows of W_out
        int row = i >> 6;
        f16x4 r = {};
        if (row < NCLS) {
            float4 v = Wout[i];
            r[0] = (f16)v.x; r[1] = (f16)v.y; r[2] = (f16)v.z; r[3] = (f16)v.w;
        }
        Wout16[i] = r;
    }
}

// ---------------------------------------------------------------------------
// Leaf kernel (round-7 structure): block owns 16 output cols; Wiou 16-col
// tile (3 gates, 24 KB) staged in LDS in MFMA-fragment order. Each wave
// loops 16 row-tiles of 16 leaves with 1-deep A-prefetch. Grid (64, 16):
// row-chunks in grid.x, col-block in grid.y (measured-best orientation).
// ---------------------------------------------------------------------------
#define LEAF_TPW 16
__global__ __launch_bounds__(256) void leaf_kernel(
    const int* __restrict__ x, const f16* __restrict__ Emb16,
    const f16* __restrict__ Wiou16, const float* __restrict__ b_iou,
    f16* __restrict__ h16, f16* __restrict__ cT)
{
    __shared__ f16 wlds[1536 * 8];             // 24 KB: [mat][ks][quad][col] frags
    __shared__ f16 ldsh[4][16 * LDSH_S];

    const int tid  = threadIdx.x;
    const int lane = tid & 63;
    const int w    = tid >> 6;
    const int quad = lane >> 4;
    const int l15  = lane & 15;
    const int qk   = quad * 8;
    const int cb0  = blockIdx.y * 16;          // block's 16 cols

    // Stage weights (frag f = mat*512 + ks*64 + quad*16 + col)
    #pragma unroll
    for (int i = 0; i < 6; ++i) {
        int f = i * 256 + tid;
        int mat = f >> 9, r = f & 511, ks = r >> 6, q = (r >> 4) & 3, c = r & 15;
        *(f16x8*)(wlds + f * 8) = *(const f16x8*)(Wiou16 +
            (mat * 256 + cb0 + c) * HDIM + ks * 32 + q * 8);
    }
    __syncthreads();

    const float bi = b_iou[cb0 + l15];
    const float bo = b_iou[256 + cb0 + l15];
    const float bu = b_iou[512 + cb0 + l15];

    const int row0 = (blockIdx.x * 4 + w) * (LEAF_TPW * 16);  // wave's rows

    // Prefetch tile 0 (16 leaf rows are node-contiguous: 16 | 2048)
    int nodeRow = (row0 >> 11) * M_NODES + 2047 + (row0 & 2047);
    int embBase = x[nodeRow + l15] * HDIM;
    f16x8 a[8];
    #pragma unroll
    for (int ks = 0; ks < 8; ++ks)
        a[ks] = *(const f16x8*)(Emb16 + embBase + ks * 32 + qk);

    for (int rt = 0; rt < LEAF_TPW; ++rt) {
        const int rw = row0 + rt * 16;
        const int curNode = nodeRow;
        f16x8 ac[8];
        #pragma unroll
        for (int ks = 0; ks < 8; ++ks) ac[ks] = a[ks];

        if (rt + 1 < LEAF_TPW) {               // prefetch next tile
            const int rwn = rw + 16;
            nodeRow = (rwn >> 11) * M_NODES + 2047 + (rwn & 2047);
            embBase = x[nodeRow + l15] * HDIM;
            #pragma unroll
            for (int ks = 0; ks < 8; ++ks)
                a[ks] = *(const f16x8*)(Emb16 + embBase + ks * 32 + qk);
        }

        f32x4 acc[3] = {};
        #pragma unroll
        for (int ks = 0; ks < 8; ++ks) {
            #pragma unroll
            for (int mat = 0; mat < 3; ++mat) {
                f16x8 wf = *(const f16x8*)(wlds +
                    ((mat * 8 + ks) * 64 + quad * 16 + l15) * 8);
                acc[mat] = __builtin_amdgcn_mfma_f32_16x16x32_f16(
                    ac[ks], wf, acc[mat], 0, 0, 0);
            }
        }

        // Epilogue (leaves: h_sum = fc_sum = 0)
        f16x4 cv;
        #pragma unroll
        for (int r = 0; r < 4; ++r) {
            float i_ = acc[0][r] + bi;
            float o_ = acc[1][r] + bo;
            float u_ = acc[2][r] + bu;
            float c  = sigf(i_) * tanh_fast(u_);
            float h  = sigf(o_) * tanh_fast(c);
            cv[r] = (f16)c;
            ldsh[w][(quad * 4 + r) * LDSH_S + l15] = (f16)h;
        }
        *(f16x4*)(cT + (cb0 + l15) * LEAFROWS + rw + quad * 4) = cv;

        // Wave-local drain of 16x16 h tile (8B stores)
        {
            int row_l = lane >> 2, cpos = (lane & 3) * 4;
            f16x4 v = *(const f16x4*)(&ldsh[w][row_l * LDSH_S + cpos]);
            *(f16x4*)(h16 + (curNode + row_l) * HDIM + cb0 + cpos) = v;
        }
    }
}

// ---------------------------------------------------------------------------
// Fused level kernel (round-7 datapath): block owns 16 cols. Work unit =
// 16 parents (32 children). Single K-loop reads the 32 child-h rows once;
// each weight fragment feeds 2 MFMAs. Parent iou = in-lane pair-sum of
// adjacent C/D regs; fc = f0*c0+f1*c1 in-lane.
// STAGE: weights in LDS (big levels) vs direct L1/L2-hot global (small).
// Grid (gx, 16): row-chunks in grid.x (round-7 orientation).
// ---------------------------------------------------------------------------
template <bool STAGE>
__global__ __launch_bounds__(256) void fused_level_kernel(
    const f16* __restrict__ Uiou16, const f16* __restrict__ Uf16,
    const float* __restrict__ b_iou, const float* __restrict__ b_f,
    f16* __restrict__ h16, const f16* __restrict__ cT_child,
    f16* __restrict__ cT_parent, int l, int rows_p, int tpw)
{
    __shared__ f16 wlds[STAGE ? 2048 * 8 : 8]; // 32 KB: mat0=Uf, mat1..3=Uiou
    __shared__ f16 ldsh[4][16 * LDSH_S];

    const int tid  = threadIdx.x;
    const int lane = tid & 63;
    const int w    = tid >> 6;
    const int quad = lane >> 4;
    const int l15  = lane & 15;
    const int qk   = quad * 8;
    const int cb0  = blockIdx.y * 16;

    if (STAGE) {
        #pragma unroll
        for (int i = 0; i < 8; ++i) {
            int f = i * 256 + tid;
            int mat = f >> 9, r = f & 511, ks = r >> 6, q = (r >> 4) & 3, c = r & 15;
            const f16* src = (mat == 0)
                ? (Uf16 + (cb0 + c) * HDIM + ks * 32 + q * 8)
                : (Uiou16 + ((mat - 1) * 256 + cb0 + c) * HDIM + ks * 32 + q * 8);
            *(f16x8*)(wlds + f * 8) = *(const f16x8*)src;
        }
        __syncthreads();
    }

    const float bi  = b_iou[cb0 + l15];
    const float bo  = b_iou[256 + cb0 + l15];
    const float bu  = b_iou[512 + cb0 + l15];
    const float bfv = b_f[cb0 + l15];
    const int lc = l + 1;
    const int maskc = (1 << lc) - 1;
    const int maskp = (1 << l) - 1;
    const int rows_c = rows_p * 2;

    const int p0 = blockIdx.x * (tpw * 64);

    for (int pt = 0; pt < tpw; ++pt) {
        const int pw = p0 + (pt * 4 + w) * 16;   // tile's first parent
        if (pw >= rows_p) continue;
        const int cw = 2 * pw;

        int childBase0, childBase1;
        {
            int cl0 = cw + l15;
            childBase0 = ((cl0 >> lc) * M_NODES + maskc + (cl0 & maskc)) * HDIM;
            int cl1 = cw + 16 + l15;
            childBase1 = ((cl1 >> lc) * M_NODES + maskc + (cl1 & maskc)) * HDIM;
        }

        f32x4 accf0 = {}, accf1 = {};
        f32x4 au0[3] = {}, au1[3] = {};
        #pragma unroll
        for (int ks = 0; ks < 8; ++ks) {
            const int k0 = ks * 32 + qk;
            f16x8 a0 = *(const f16x8*)(h16 + childBase0 + k0);
            f16x8 a1 = *(const f16x8*)(h16 + childBase1 + k0);
            f16x8 wfF = STAGE
                ? *(const f16x8*)(wlds + (ks * 64 + quad * 16 + l15) * 8)
                : *(const f16x8*)(Uf16 + (cb0 + l15) * HDIM + k0);
            accf0 = __builtin_amdgcn_mfma_f32_16x16x32_f16(a0, wfF, accf0, 0, 0, 0);
            accf1 = __builtin_amdgcn_mfma_f32_16x16x32_f16(a1, wfF, accf1, 0, 0, 0);
            #pragma unroll
            for (int m = 0; m < 3; ++m) {
                f16x8 wm = STAGE
                    ? *(const f16x8*)(wlds + (((m + 1) * 8 + ks) * 64 + quad * 16 + l15) * 8)
                    : *(const f16x8*)(Uiou16 + (m * 256 + cb0 + l15) * HDIM + k0);
                au0[m] = __builtin_amdgcn_mfma_f32_16x16x32_f16(a0, wm, au0[m], 0, 0, 0);
                au1[m] = __builtin_amdgcn_mfma_f32_16x16x32_f16(a1, wm, au1[m], 0, 0, 0);
            }
        }

        // Epilogue: two child sets -> parents pw..pw+7 and pw+8..pw+15
        #pragma unroll
        for (int s = 0; s < 2; ++s) {
            const f32x4& af = s ? accf1 : accf0;
            const f32x4* au = s ? au1 : au0;
            const int csr = cw + s * 16;          // child rows of this set
            f16x4 cc = *(const f16x4*)(cT_child +
                (cb0 + l15) * rows_c + csr + quad * 4);
            f16x2 cpack;
            #pragma unroll
            for (int pr = 0; pr < 2; ++pr) {
                float f0 = sigf(af[2 * pr]     + bfv);
                float f1 = sigf(af[2 * pr + 1] + bfv);
                float fc = f0 * (float)cc[2 * pr] + f1 * (float)cc[2 * pr + 1];
                float i_ = au[0][2 * pr] + au[0][2 * pr + 1] + bi;
                float o_ = au[1][2 * pr] + au[1][2 * pr + 1] + bo;
                float u_ = au[2][2 * pr] + au[2][2 * pr + 1] + bu;
                float c  = sigf(i_) * tanh_fast(u_) + fc;
                float h  = sigf(o_) * tanh_fast(c);
                cpack[pr] = (f16)c;
                ldsh[w][(s * 8 + quad * 2 + pr) * LDSH_S + l15] = (f16)h;
            }
            *(f16x2*)(cT_parent + (cb0 + l15) * rows_p + pw + s * 8 + quad * 2) = cpack;
        }

        // Wave-local drain of 16-parent x 16-col h tile (8B stores)
        {
            int prow = lane >> 2, cpos = (lane & 3) * 4;
            int p = pw + prow;
            int b = p >> l, tt = p & maskp;
            int node = b * M_NODES + (1 << l) - 1 + tt;
            f16x4 v = *(const f16x4*)(&ldsh[w][prow * LDSH_S + cpos]);
            *(f16x4*)(h16 + node * HDIM + cb0 + cpos) = v;
        }
    }
}

// ---------------------------------------------------------------------------
// Output: out = h_all @ W_out^T + b_out (N padded 20->32). Persistent
// weights (64 VGPRs); wave owns 4 consecutive tiles with 1-deep prefetch.
// ---------------------------------------------------------------------------
__global__ __launch_bounds__(256) void out_kernel(
    const f16* __restrict__ h16, const f16* __restrict__ Wout16,
    const float* __restrict__ bout, float* __restrict__ out)
{
    const int lane = threadIdx.x & 63;
    const int w    = threadIdx.x >> 6;
    const int quad = lane >> 4;
    const int l15  = lane & 15;
    const int qk   = quad * 8;

    f16x8 wfk[2][8];
    #pragma unroll
    for (int cf = 0; cf < 2; ++cf)
        #pragma unroll
        for (int ks = 0; ks < 8; ++ks)
            wfk[cf][ks] = *(const f16x8*)(Wout16 +
                (cf * 16 + l15) * HDIM + ks * 32 + qk);
    float bo[2];
    #pragma unroll
    for (int cf = 0; cf < 2; ++cf) {
        int col = cf * 16 + l15;
        bo[cf] = bout[col < NCLS ? col : 0];
    }

    const int ntotal = N_NODES / 16;               // 8190
    const int t0     = blockIdx.x * 16 + w * 4;    // wave's first tile
    const int tn     = (t0 >= ntotal) ? 0 : ((ntotal - t0 < 4) ? ntotal - t0 : 4);
    if (tn <= 0) return;

    f16x8 a[8];
    #pragma unroll
    for (int ks = 0; ks < 8; ++ks)
        a[ks] = *(const f16x8*)(h16 + (t0 * 16 + l15) * HDIM + ks * 32 + qk);

    for (int i = 0; i < tn; ++i) {
        const int rw = (t0 + i) * 16;
        f16x8 ac[8];
        #pragma unroll
        for (int ks = 0; ks < 8; ++ks) ac[ks] = a[ks];

        {
            const int tnx = (i + 1 < tn) ? t0 + i + 1 : t0 + i;
            #pragma unroll
            for (int ks = 0; ks < 8; ++ks)
                a[ks] = *(const f16x8*)(h16 + (tnx * 16 + l15) * HDIM + ks * 32 + qk);
        }

        f32x4 acc[2] = {};
        #pragma unroll
        for (int ks = 0; ks < 8; ++ks)
            #pragma unroll
            for (int cf = 0; cf < 2; ++cf)
                acc[cf] = __builtin_amdgcn_mfma_f32_16x16x32_f16(
                    ac[ks], wfk[cf][ks], acc[cf], 0, 0, 0);

        #pragma unroll
        for (int cf = 0; cf < 2; ++cf) {
            const int col = cf * 16 + l15;
            if (col < NCLS) {
                #pragma unroll
                for (int r = 0; r < 4; ++r)
                    out[(rw + quad * 4 + r) * NCLS + col] = acc[cf][r] + bo[cf];
            }
        }
    }
}

// ---------------------------------------------------------------------------
extern "C" void kernel_launch(void* const* d_in, const int* in_sizes, int n_in,
                              void* d_out, int out_size, void* d_ws, size_t ws_size,
                              hipStream_t stream)
{
    const int*   x     = (const int*)d_in[0];
    // d_in[1] = x_mask: leaf structure is static — folded into indexing.
    const float* Emb   = (const float*)d_in[2];
    const float* W_iou = (const float*)d_in[3];
    const float* b_iou = (const float*)d_in[4];
    const float* U_iou = (const float*)d_in[5];
    const float* U_f   = (const float*)d_in[6];
    const float* b_f   = (const float*)d_in[7];
    const float* W_out = (const float*)d_in[8];
    const float* b_out = (const float*)d_in[9];
    float* out = (float*)d_out;

    char* ws = (char*)d_ws;
    size_t off = 0;
    auto take = [&](size_t bytes) -> char* {
        char* p = ws + off; off += (bytes + 255) & ~(size_t)255; return p;
    };
    f16* h16    = (f16*)take((size_t)N_NODES * HDIM * 2);
    f16* cA     = (f16*)take((size_t)HDIM * LEAFROWS * 2);        // [256][65536]
    f16* cB     = (f16*)take((size_t)HDIM * (LEAFROWS / 2) * 2);  // [256][32768]
    f16* Emb16  = (f16*)take((size_t)VOCAB * HDIM * 2);
    f16* Wiou16 = (f16*)take((size_t)768 * HDIM * 2);
    f16* Uiou16 = (f16*)take((size_t)768 * HDIM * 2);
    f16* Uf16   = (f16*)take((size_t)HDIM * HDIM * 2);
    f16* Wout16 = (f16*)take((size_t)32 * HDIM * 2);

    cvt_kernel<<<VOCAB * HDIM / 4 / 256, 256, 0, stream>>>(
        (const float4*)Emb, (const float4*)W_iou, (const float4*)U_iou,
        (const float4*)U_f, (const float4*)W_out,
        (f16x4*)Emb16, (f16x4*)Wiou16, (f16x4*)Uiou16, (f16x4*)Uf16,
        (f16x4*)Wout16);

    // Leaves: grid (64 row-chunks, 16 col-blocks); 16 tiles/wave
    leaf_kernel<<<dim3(LEAFROWS / (4 * 16 * LEAF_TPW), 16), 256, 0, stream>>>(
        x, Emb16, Wiou16, b_iou, h16, cA);

    // Levels 10..0, fused fgate+iou, ping-pong transposed c buffers.
    // tpw targets gx<=64 blocks.x (~1024 blocks) to cut weight-staging refetch.
    f16* cin  = cA;
    f16* cout_ = cB;
    for (int l = 10; l >= 0; --l) {
        int rows_p = B_TREES << l;
        int tpw    = rows_p / 4096; if (tpw < 1) tpw = 1;
        int gx     = (rows_p + tpw * 64 - 1) / (tpw * 64);
        if (rows_p >= 8192)
            fused_level_kernel<true><<<dim3(gx, 16), 256, 0, stream>>>(
                Uiou16, Uf16, b_iou, b_f, h16, cin, cout_, l, rows_p, tpw);
        else
            fused_level_kernel<false><<<dim3(gx, 16), 256, 0, stream>>>(
                Uiou16, Uf16, b_iou, b_f, h16, cin, cout_, l, rows_p, tpw);
        f16* t = cin; cin = cout_; cout_ = t;
    }

    out_kernel<<<dim3((N_NODES / 16 + 15) / 16), 256, 0, stream>>>(
        h16, Wout16, b_out, out);
}